// Round 5
// baseline (1163.839 us; speedup 1.0000x reference)
//
#include <hip/hip_runtime.h>
#include <math.h>

#define KP 6
#define BATCH 256
#define DIM 768
#define NMEM 32768
#define NXBLK (NMEM / 128)   // col-blocks per row = 256
#define NROWS (KP * BATCH)   // 1536

typedef __attribute__((ext_vector_type(8))) short bf16x8;
typedef __attribute__((ext_vector_type(4))) float f32x4;

__device__ inline uint bf16rne(float x) {
  uint u = __builtin_bit_cast(uint, x);
  return (u + 0x7fffu + ((u >> 16) & 1u)) >> 16;
}
__device__ inline uint pk2(float lo, float hi) {
  return bf16rne(lo) | (bf16rne(hi) << 16);
}
// XOR swizzle: flips 16B-unit index (bits 4-5) with row bits 1-2 (row stride 64B).
__device__ inline int swz(int b) { return b ^ (((b >> 7) & 3) << 4); }

__device__ inline void gld_lds16(const ushort* g, ushort* l) {
  __builtin_amdgcn_global_load_lds(
      (const __attribute__((address_space(1))) void*)g,
      (__attribute__((address_space(3))) void*)l, 16, 0, 0);
}

// ---------------- prep: fp64 inv-norms + bf16 copies ----------------

__global__ __launch_bounds__(256) void prep_kernel(const float* __restrict__ X,
                                                   ushort* __restrict__ Xb,
                                                   double* __restrict__ invX,
                                                   int nrows) {
  int wid = threadIdx.x >> 6, lane = threadIdx.x & 63;
  int row = blockIdx.x * 4 + wid;
  if (row >= nrows) return;
  const float* x = X + (size_t)row * DIM;
  ushort* xb = Xb + (size_t)row * DIM;
  double s = 0.0;
#pragma unroll
  for (int i = 0; i < 3; ++i) {
    int d = i * 256 + lane * 4;
    float4 v = *reinterpret_cast<const float4*>(x + d);
    s += (double)v.x * v.x + (double)v.y * v.y;
    s += (double)v.z * v.z + (double)v.w * v.w;
    uint2 p; p.x = pk2(v.x, v.y); p.y = pk2(v.z, v.w);
    *reinterpret_cast<uint2*>(xb + d) = p;
  }
  for (int off = 32; off > 0; off >>= 1) s += __shfl_down(s, off);
  if (lane == 0) invX[row] = 1.0 / fmax(sqrt(s), 1e-12);
}

// ---------------- bf16 MFMA GEMM, 2-phase dbuf, fused top-4 + soft zeros ----

#define GBM 128
#define GBN 128
#define GBK 32
#define NKT (DIM / GBK)  // 24
#define CHS 132          // scan chunk row stride (132 mod 32 = 4 -> 2-way max)

__global__ __launch_bounds__(256) void gemm_kernel(
    const ushort* __restrict__ Fb, const ushort* __restrict__ Mb,
    const double* __restrict__ invF, const double* __restrict__ invM,
    float* __restrict__ sim, float* __restrict__ soft, float2* __restrict__ P) {
  // bijective XCD swizzle: 3072 wg = 8 xcd x 384; m-tile pair adjacent per XCD
  int lin = blockIdx.x;
  int wg = (lin & 7) * 384 + (lin >> 3);
  int k = wg >> 9;
  int bm0 = (wg & 1) * GBM;
  int ntile = (wg >> 1) & 255;
  int bn0 = ntile * GBN;
  const ushort* Fk = Fb + (size_t)k * BATCH * DIM;
  const ushort* Mk = Mb + (size_t)k * NMEM * DIM;

  __shared__ __align__(16) char smem[32768];
  ushort* A0 = (ushort*)smem;             // 8 KB each
  ushort* B0 = (ushort*)(smem + 8192);
  ushort* A1 = (ushort*)(smem + 16384);
  ushort* B1 = (ushort*)(smem + 24576);

  int tid = threadIdx.x;
  int lane = tid & 63, wave = tid >> 6;
  int wr = (wave >> 1) * 64, wc = (wave & 1) * 64;
  int l15 = lane & 15, lch = lane >> 4;
  int rgrp = lch << 2;

  // staging: lane l -> row wave*32+(l>>2); global col chunk PRE-SWIZZLED so the
  // linear gload_lds dest ends up XOR-swizzled: chunk = (l&3) ^ ((l>>3)&3)
  int srow = wave * 32 + (lane >> 2);
  int scol = ((lane & 3) ^ ((lane >> 3) & 3)) * 8;
  const ushort* gA0 = Fk + (size_t)(bm0 + srow) * DIM + scol;
  const ushort* gA1 = gA0 + (size_t)16 * DIM;
  const ushort* gB0 = Mk + (size_t)(bn0 + srow) * DIM + scol;
  const ushort* gB1 = gB0 + (size_t)16 * DIM;
  int lo0 = (wave * 32) * GBK, lo1 = (wave * 32 + 16) * GBK;

  // swizzled fragment byte-offsets (K-invariant, within an 8KB buffer)
  int aoff[4], boff[4];
#pragma unroll
  for (int i = 0; i < 4; ++i) {
    aoff[i] = swz((wr + i * 16 + l15) * 64 + lch * 16);
    boff[i] = swz((wc + i * 16 + l15) * 64 + lch * 16);
  }

  f32x4 acc[4][4];
#pragma unroll
  for (int i = 0; i < 4; ++i)
#pragma unroll
    for (int j = 0; j < 4; ++j) acc[i][j] = (f32x4){0.f, 0.f, 0.f, 0.f};

#define STAGE(t, A, B)                         \
  do {                                         \
    int kk_ = (t) * GBK;                       \
    gld_lds16(gA0 + kk_, (A) + lo0);           \
    gld_lds16(gA1 + kk_, (A) + lo1);           \
    gld_lds16(gB0 + kk_, (B) + lo0);           \
    gld_lds16(gB1 + kk_, (B) + lo1);           \
  } while (0)

#define COMPUTE(A, B)                                                          \
  do {                                                                         \
    bf16x8 af[4], bfr[4];                                                      \
    _Pragma("unroll") for (int i = 0; i < 4; ++i) {                            \
      af[i] = *reinterpret_cast<const bf16x8*>((char*)(A) + aoff[i]);          \
      bfr[i] = *reinterpret_cast<const bf16x8*>((char*)(B) + boff[i]);         \
    }                                                                          \
    _Pragma("unroll") for (int i = 0; i < 4; ++i)                              \
        _Pragma("unroll") for (int j = 0; j < 4; ++j) acc[i][j] =              \
            __builtin_amdgcn_mfma_f32_16x16x32_bf16(af[i], bfr[j], acc[i][j],  \
                                                    0, 0, 0);                  \
  } while (0)

  STAGE(0, A0, B0);
  __syncthreads();
  for (int t = 0; t < NKT; t += 2) {
    STAGE(t + 1, A1, B1);       // in flight while computing tile t
    COMPUTE(A0, B0);
    __syncthreads();            // drains vmcnt (stage t+1 landed) + lgkm
    if (t + 2 < NKT) STAGE(t + 2, A0, B0);
    COMPUTE(A1, B1);
    __syncthreads();
  }

  // ---------- epilogue ----------
  size_t kb = (size_t)k * BATCH;
  float fi[4][4];
#pragma unroll
  for (int i = 0; i < 4; ++i)
#pragma unroll
    for (int r = 0; r < 4; ++r)
      fi[i][r] = (float)invF[kb + bm0 + wr + i * 16 + rgrp + r];
  float im[4];
#pragma unroll
  for (int j = 0; j < 4; ++j)
    im[j] = (float)invM[(size_t)k * NMEM + bn0 + wc + j * 16 + l15];

  // direct sim stores from registers (each instr: 4 rows x 64B lines)
#pragma unroll
  for (int i = 0; i < 4; ++i)
#pragma unroll
    for (int j = 0; j < 4; ++j) {
      size_t rbase = kb + bm0 + wr + i * 16 + rgrp;
      int c = bn0 + wc + j * 16 + l15;
#pragma unroll
      for (int r = 0; r < 4; ++r)
        sim[(rbase + r) * NMEM + c] = acc[i][j][r] * fi[i][r] * im[j];
    }

  // soft zero-block (coalesced float4), scatter happens later in merge
  {
    const f32x4 z = (f32x4){0.f, 0.f, 0.f, 0.f};
#pragma unroll
    for (int p = 0; p < 16; ++p) {
      int u = p * 256 + tid;
      int row = u >> 5, unit = u & 31;
      *reinterpret_cast<f32x4*>(soft + (kb + bm0 + row) * NMEM + bn0 + unit * 4) = z;
    }
  }

  // per-row block top-4 via 4 quarter-chunks of 32 rows (LDS reused post-loop)
  float* chunk = (float*)smem;                  // 32*CHS*4 = 16896 B
  float2* lists = (float2*)(smem + 24576);      // 32*8*4*8 = 8192 B
  for (int qt = 0; qt < 4; ++qt) {
    __syncthreads();  // chunk+lists free (K-loop or previous quarter done)
    if (wr == (qt >> 1) * 64) {
      int ibase = (qt & 1) * 2;
#pragma unroll
      for (int ii = 0; ii < 2; ++ii) {
        int i = ibase + ii;
        int rc0 = ii * 16 + rgrp;
#pragma unroll
        for (int j = 0; j < 4; ++j)
#pragma unroll
          for (int r = 0; r < 4; ++r)
            chunk[(rc0 + r) * CHS + wc + j * 16 + l15] =
                acc[i][j][r] * fi[i][r] * im[j];
      }
    }
    __syncthreads();
    int rc = tid >> 3, q8 = tid & 7;  // 8 threads per row, 16 cols each
    float v4[4] = {-INFINITY, -INFINITY, -INFINITY, -INFINITY};
    int i4[4] = {0, 0, 0, 0};
#pragma unroll
    for (int j = 0; j < 16; ++j) {
      int cc = q8 + 8 * j;
      float v = chunk[rc * CHS + cc];
      if (v > v4[3]) {
        v4[3] = v; i4[3] = cc;
        if (v4[3] > v4[2]) { float t = v4[3]; v4[3] = v4[2]; v4[2] = t; int s = i4[3]; i4[3] = i4[2]; i4[2] = s; }
        if (v4[2] > v4[1]) { float t = v4[2]; v4[2] = v4[1]; v4[1] = t; int s = i4[2]; i4[2] = i4[1]; i4[1] = s; }
        if (v4[1] > v4[0]) { float t = v4[1]; v4[1] = v4[0]; v4[0] = t; int s = i4[1]; i4[1] = i4[0]; i4[0] = s; }
      }
    }
#pragma unroll
    for (int s = 0; s < 4; ++s)
      lists[(rc * 8 + q8) * 4 + s] = make_float2(v4[s], __builtin_bit_cast(float, i4[s]));
    __syncthreads();
    if (q8 == 0) {
      float mv[4] = {-INFINITY, -INFINITY, -INFINITY, -INFINITY};
      int mi[4] = {0, 0, 0, 0};
#pragma unroll
      for (int e = 0; e < 32; ++e) {
        float2 pe = lists[rc * 32 + e];
        float v = pe.x; int ix = __builtin_bit_cast(int, pe.y);
        if (v > mv[3]) {
          mv[3] = v; mi[3] = ix;
          if (mv[3] > mv[2]) { float t = mv[3]; mv[3] = mv[2]; mv[2] = t; int s = mi[3]; mi[3] = mi[2]; mi[2] = s; }
          if (mv[2] > mv[1]) { float t = mv[2]; mv[2] = mv[1]; mv[1] = t; int s = mi[2]; mi[2] = mi[1]; mi[1] = s; }
          if (mv[1] > mv[0]) { float t = mv[1]; mv[1] = mv[0]; mv[0] = t; int s = mi[1]; mi[1] = mi[0]; mi[0] = s; }
        }
      }
      float2* Prow = P + ((size_t)(kb + bm0 + qt * 32 + rc) * NXBLK + ntile) * 4;
#pragma unroll
      for (int s = 0; s < 4; ++s)
        Prow[s] = make_float2(mv[s], __builtin_bit_cast(float, mi[s] + bn0));
    }
  }
#undef STAGE
#undef COMPUTE
}

// ---------------- merge partials + fp64 refine + softmax + entropy ----------

__global__ __launch_bounds__(256) void merge_kernel(
    const float* __restrict__ F, const float* __restrict__ M,
    const double* __restrict__ invF, const double* __restrict__ invM,
    const float2* __restrict__ P, float* __restrict__ soft,
    float* __restrict__ ent) {
  int kb = blockIdx.x;  // 0..1535
  int k = kb / BATCH;
  int tid = threadIdx.x;
  float* orow = soft + (size_t)kb * NMEM;

  __shared__ float sval[1024];
  __shared__ int   sidx[1024];
  const float2* Prow = P + (size_t)kb * NXBLK * 4;
#pragma unroll
  for (int j = 0; j < 4; ++j) {
    float2 e = Prow[tid * 4 + j];
    sval[tid * 4 + j] = e.x;
    sidx[tid * 4 + j] = __builtin_bit_cast(int, e.y);
  }
  __syncthreads();

  __shared__ float rv[256]; __shared__ int rp[256];
  __shared__ float cand_v[8]; __shared__ int cand_i[8];
  for (int r = 0; r < 8; ++r) {
    float best = -INFINITY; int bpos = tid * 4;
#pragma unroll
    for (int j = 0; j < 4; ++j) {
      float v = sval[tid * 4 + j];
      if (v > best) { best = v; bpos = tid * 4 + j; }
    }
    rv[tid] = best; rp[tid] = bpos;
    __syncthreads();
    for (int st = 128; st > 0; st >>= 1) {
      if (tid < st && rv[tid + st] > rv[tid]) { rv[tid] = rv[tid + st]; rp[tid] = rp[tid + st]; }
      __syncthreads();
    }
    if (tid == 0) {
      cand_v[r] = rv[0]; cand_i[r] = sidx[rp[0]];
      sval[rp[0]] = -INFINITY;
    }
    __syncthreads();
  }

  // fp64 refinement of the 8 candidates (exact re-ranking at the 5/6 boundary)
  __shared__ double dred[256];
  __shared__ double cval[8];
  const float* fr = F + (size_t)kb * DIM;
  double invf = invF[kb];
  for (int c = 0; c < 8; ++c) {
    const float* mr = M + ((size_t)k * NMEM + cand_i[c]) * DIM;
    double s = 0.0;
    for (int d = tid; d < DIM; d += 256) s += (double)fr[d] * (double)mr[d];
    dred[tid] = s; __syncthreads();
    for (int st = 128; st > 0; st >>= 1) {
      if (tid < st) dred[tid] += dred[tid + st];
      __syncthreads();
    }
    if (tid == 0) cval[c] = dred[0] * invf * invM[(size_t)k * NMEM + cand_i[c]];
    __syncthreads();
  }

  if (tid == 0) {
    int ord[8];
    for (int i = 0; i < 8; ++i) ord[i] = i;
    for (int i = 0; i < 5; ++i) {
      int best = i;
      for (int j = i + 1; j < 8; ++j) {
        float fa = (float)cval[ord[j]], fb = (float)cval[ord[best]];
        bool better = (fa != fb) ? (fa > fb) : (cand_i[ord[j]] < cand_i[ord[best]]);
        if (better) best = j;
      }
      int t = ord[i]; ord[i] = ord[best]; ord[best] = t;
    }
    float v5[5]; int i5[5];
    float vmax = -INFINITY;
    for (int i = 0; i < 5; ++i) {
      v5[i] = cand_v[ord[i]]; i5[i] = cand_i[ord[i]];
      vmax = fmaxf(vmax, v5[i]);
    }
    float e[5], Z = 0.f;
    float xm = vmax / 3.0f;
    for (int i = 0; i < 5; ++i) { e[i] = expf(v5[i] / 3.0f - xm); Z += e[i]; }
    float ent_s = 0.f;
    for (int i = 0; i < 5; ++i) {
      float p = e[i] / Z;
      orow[i5[i]] = p;
      ent_s += p * logf(p);
    }
    float tiny = 1e-8f * logf(1e-8f);
    ent[kb] = -(ent_s + (float)(NMEM - 5) * tiny);
  }
}

// ---------------- entropy weights ----------------

__global__ __launch_bounds__(256) void w_kernel(const float* __restrict__ ent,
                                                float* __restrict__ wout) {
  int k = blockIdx.x; int tid = threadIdx.x;
  float e = ent[k * BATCH + tid];
  float wv = expf(-e);
  __shared__ float red[256];
  red[tid] = wv; __syncthreads();
  for (int st = 128; st > 0; st >>= 1) {
    if (tid < st) red[tid] += red[tid + st];
    __syncthreads();
  }
  float mean = red[0] / (float)BATCH;
  wout[k * BATCH + tid] = wv / (mean + 1e-8f);
}

// ---------------- launch ----------------

extern "C" void kernel_launch(void* const* d_in, const int* in_sizes, int n_in,
                              void* d_out, int out_size, void* d_ws, size_t ws_size,
                              hipStream_t stream) {
  (void)in_sizes; (void)n_in; (void)out_size; (void)ws_size;
  const float* F = (const float*)d_in[0];   // [KP, BATCH, DIM] fp32
  const float* M = (const float*)d_in[1];   // [KP, NMEM, DIM] fp32
  float* out = (float*)d_out;
  size_t simsz = (size_t)KP * BATCH * NMEM;
  float* soft = out;
  float* sim = out + simsz;
  float* wout = out + 2 * simsz;

  // workspace layout (~320 MB of the ~2.4 GB ws)
  ushort* Mb = (ushort*)d_ws;                               // KP*NMEM*DIM bf16
  ushort* Fb = Mb + (size_t)KP * NMEM * DIM;                // KP*BATCH*DIM bf16
  double* invM = (double*)(Fb + (size_t)KP * BATCH * DIM);  // KP*NMEM f64
  double* invF = invM + (size_t)KP * NMEM;                  // KP*BATCH f64
  float* ent = (float*)(invF + KP * BATCH);                 // KP*BATCH f32
  float2* P = (float2*)(ent + NROWS);                       // NROWS*NXBLK*4 float2

  prep_kernel<<<KP * BATCH / 4, 256, 0, stream>>>(F, Fb, invF, KP * BATCH);
  prep_kernel<<<KP * NMEM / 4, 256, 0, stream>>>(M, Mb, invM, KP * NMEM);
  gemm_kernel<<<(BATCH / GBM) * (NMEM / GBN) * KP, 256, 0, stream>>>(Fb, Mb, invF, invM, sim, soft, P);
  merge_kernel<<<NROWS, 256, 0, stream>>>(F, M, invF, invM, P, soft, ent);
  w_kernel<<<KP, 256, 0, stream>>>(ent, wout);
}